// Round 5
// baseline (6340.852 us; speedup 1.0000x reference)
//
#include <hip/hip_runtime.h>
#include <hip/hip_bf16.h>
#include <hip/hip_cooperative_groups.h>

namespace cg = cooperative_groups;

#define N_NEUR 2000
#define N_E    1600
#define KPAD   2048
#define NCOND  96
#define NSTEP  60
#define NAVG   15

#define DEGF   0.017453292519943295f
#define TWO_DEG 0.03490658503988659f

typedef __attribute__((ext_vector_type(8))) short bf16x8;
typedef __attribute__((ext_vector_type(4))) float f32x4;

// ---------------- Ricciardi transfer function ----------------
__device__ __forceinline__ float f_ricci(float x){
    float t = -x / (1.0f + x);
    float p = 0.14805913578876898f;
    p = fmaf(p, t, 0.64290613877355551f);
    p = fmaf(p, t, 1.0616084849547165f);
    p = fmaf(p, t, 0.93524391761244940f);
    p = fmaf(p, t, 0.62718906618071668f);
    p = fmaf(p, t, 0.32171431660633076f);
    p = fmaf(p, t, 0.32056016125642045f);
    p = fmaf(p, t, 0.77373949685442023f);
    p = fmaf(p, t, 0.22757881388024176f);
    return logf(2.0f * x + 1.0f) + p * t;
}

__device__ __forceinline__ float g_ricci(float x){
    float z = x / (2.0f + x);
    float z2 = z * z, z3 = z2 * z, z4 = z2 * z2, z5 = z4 * z, z6 = z3 * z3, z7 = z6 * z, z8 = z4 * z4;
    float en = 3.5441754117462949f * z - 7.0529131065835378f * z2 - 56.532378057580381f * z3
             + 279.56761105465944f * z4 - 520.37554793489681f * z5
             + 456.58245777026514f * z6 - 155.73340457809226f * z7;
    float de = 1.0f - 4.1357968834226053f * z - 7.2984226138266743f * z2
             + 98.656602235468327f * z3 - 334.20436223415163f * z4
             + 601.08633903294185f * z5 - 599.58577549598340f * z6
             + 277.18420330693891f * z7 - 16.445022798669722f * z8;
    return en / de;
}

__device__ __forceinline__ float phi_rate(float mu, float sigma, float tau_ref){
    const float tau = 0.01f;
    float xp = mu / sigma;
    float xm = (mu - 20.0f) / sigma;
    float r;
    if (xm > 0.0f){
        r = 1.0f / (f_ricci(xp) - f_ricci(xm));
    } else if (xp > 0.0f){
        float nxm = fminf(-xm, 9.0f);
        r = 1.0f / (f_ricci(xp) + expf(nxm * nxm) * g_ricci(nxm));
    } else {
        float nxp = fminf(fmaxf(-xp, 0.0f), 9.0f);
        float nxm = fminf(-xm, 9.0f);
        float arg = g_ricci(nxm) - expf(nxp * nxp - nxm * nxm) * g_ricci(nxp);
        r = expf(-nxm * nxm - logf(fmaxf(arg, 1e-12f)));
    }
    return 1.0f / (tau_ref + tau / fmaxf(r, 1e-12f));
}

__device__ __forceinline__ float pref_of(int n){
    return (n < N_E) ? (float)n * (179.99f / 1599.0f)
                     : (float)(n - N_E) * (179.99f / 399.0f);
}

__device__ __forceinline__ unsigned short bf16_rne(float f){
    unsigned int u = __float_as_uint(f);
    u = (u + 0x7fffu + ((u >> 16) & 1u)) >> 16;
    return (unsigned short)u;
}

// ---------------- weight build: Wh, Wl (split), W2h, padded to 2048x2048 ----------------
__global__ __launch_bounds__(256) void build_w_kernel(
    const float* __restrict__ jp, const float* __restrict__ pp,
    const float* __restrict__ wp, const float* __restrict__ rnd,
    unsigned short* __restrict__ Wh, unsigned short* __restrict__ Wl,
    unsigned short* __restrict__ W2h)
{
    int e = blockIdx.x * 256 + threadIdx.x;     // over 2048*2048
    int i = e >> 11;
    int j = e & (KPAD - 1);
    float w = 0.0f;
    if (i < N_NEUR && j < N_NEUR){
        int isIi = (i >= N_E) ? 1 : 0;
        int isIj = (j >= N_E) ? 1 : 0;
        int conn = 2 * isIj + isIi;
        float J  = expf(jp[conn]);
        float P  = 1.0f / (1.0f + expf(-2.0f * expf(pp[conn])));
        float Wd = expf(wp[conn]);
        float diff = fabsf(pref_of(i) - pref_of(j));
        float dw = DEGF * Wd;
        float z = expf((cosf(TWO_DEG * diff) - 1.0f) / (4.0f * dw * dw));
        float s = 1.0f / (1.0f + expf(-32.0f * (P * z - rnd[i * N_NEUR + j])));
        float sign = isIj ? -1.0f : 1.0f;
        w = sign * J * s;
    }
    unsigned short hb = bf16_rne(w);
    float hf = __uint_as_float(((unsigned int)hb) << 16);
    Wh[e] = hb;
    Wl[e] = bf16_rne(w - hf);
    W2h[e] = bf16_rne(w * w);
}

__global__ __launch_bounds__(256) void build_im_kernel(float* __restrict__ IM)
{
    int e = blockIdx.x * 256 + threadIdx.x;     // over 96*2048
    int c = e >> 11;
    int n = e & (KPAD - 1);
    if (n >= N_NEUR){ IM[e] = 0.0f; return; }
    const float contrasts[8] = {0.0f, 0.0432773f, 0.103411f, 0.186966f,
                                0.303066f, 0.464386f, 0.68854f, 1.0f};
    int ci = c / 12;
    int oi = c - ci * 12;
    float orient = (float)oi * 15.0f;
    const float dw = DEGF * 30.0f;
    float g = expf((cosf(TWO_DEG * (orient - pref_of(n))) - 1.0f) / (4.0f * dw * dw));
    IM[e] = contrasts[ci] * 20.0f * g;
}

// ---------------- persistent cooperative solver: all 60 Euler steps ----------------
// grid 250 x 512 (8 waves), 1 block/CU. Block = (tile = bid>>1 -> 16 neurons,
// half = bid&1 -> 48 conds). Wave w owns K-slice [w*256, w*256+256).
// W fragments live in VGPRs across all steps; r double-buffered in global with
// grid-wide sync + device fences per step (cross-XCD L2 coherence).
// mu  <- rh*Wh + rh*Wl + rl*Wh   (split-bf16 ~ fp32 precision)
// sg2 <- rh*W2h + rl*W2h
__global__ __launch_bounds__(512, 2) void solve_kernel(
    const unsigned short* __restrict__ Wh, const unsigned short* __restrict__ Wl,
    const unsigned short* __restrict__ W2h,
    unsigned short* __restrict__ rhA, unsigned short* __restrict__ rlA,
    unsigned short* __restrict__ rhB, unsigned short* __restrict__ rlB,
    const float* __restrict__ IM, float* __restrict__ out,
    unsigned int* __restrict__ mb)
{
    __shared__ float red[8][64][25];    // padded stride 25: conflict-free
    __shared__ float vbuf[48][16];

    cg::grid_group grid = cg::this_grid();

    const int bid  = blockIdx.x;        // 0..249
    const int tile = bid >> 1;          // 0..124
    const int half = bid & 1;
    const int t  = threadIdx.x;
    const int wv = t >> 6;
    const int ln = t & 63;
    const int nbase = tile * 16;
    const int cbase = half * 48;

    const int lrow = ln & 15;           // A-row (cond) / B-col (neuron) in frag
    const int lk8  = (ln >> 4) * 8;     // k sub-offset
    const int kw   = wv * 256 + lk8;    // wave K-slice base + lane sub-k
    const int nrow = nbase + lrow;

    // ---- preload W fragments into registers (constant across steps) ----
    const unsigned short* pwh = &Wh [nrow * KPAD + kw];
    const unsigned short* pwl = &Wl [nrow * KPAD + kw];
    const unsigned short* pw2 = &W2h[nrow * KPAD + kw];
    bf16x8 wh_f[8], wl_f[8], w2_f[8];
    #pragma unroll
    for (int s = 0; s < 8; ++s){
        wh_f[s] = *reinterpret_cast<const bf16x8*>(pwh + s * 32);
        wl_f[s] = *reinterpret_cast<const bf16x8*>(pwl + s * 32);
        w2_f[s] = *reinterpret_cast<const bf16x8*>(pw2 + s * 32);
    }

    // ---- epilogue slot precompute: slot0 = o=t, slot1 = o=t+512 (t<256) ----
    const int o0 = t, o1 = t + 512;
    const bool has1 = (o1 < 768);
    const int c_l0 = o0 >> 4, n_l0 = o0 & 15;
    const int c_l1 = o1 >> 4, n_l1 = o1 & 15;
    const int m0 = c_l0 >> 4, q0 = c_l0 & 3, lr0 = ((c_l0 & 15) >> 2) * 16 + n_l0;
    const int m1 = c_l1 >> 4, q1 = c_l1 & 3, lr1 = ((c_l1 & 15) >> 2) * 16 + n_l1;
    const int c0 = cbase + c_l0, i0n = nbase + n_l0;
    const int c1 = cbase + c_l1, i1n = nbase + n_l1;
    const float im0 = IM[c0 * KPAD + i0n];
    const float im1 = has1 ? IM[c1 * KPAD + i1n] : 0.0f;
    const bool isI0 = (i0n >= N_E), isI1 = (i1n >= N_E);
    float rf0 = 0.0f, rf1 = 0.0f;       // r state in registers

    const int ro0 = (cbase + lrow) * KPAD + kw;   // A-frag base offset

    for (int st = 0; st < NSTEP; ++st){
        const unsigned short* rh = (st & 1) ? rhB : rhA;
        const unsigned short* rl = (st & 1) ? rlB : rlA;
        unsigned short* rho = (st & 1) ? rhA : rhB;
        unsigned short* rlo = (st & 1) ? rlA : rlB;

        f32x4 accm[3], accs[3];
        #pragma unroll
        for (int m = 0; m < 3; ++m){
            accm[m] = (f32x4){0.0f, 0.0f, 0.0f, 0.0f};
            accs[m] = (f32x4){0.0f, 0.0f, 0.0f, 0.0f};
        }

        #pragma unroll
        for (int s = 0; s < 8; ++s){
            const int kk = s * 32;
            const bf16x8 ah0 = *reinterpret_cast<const bf16x8*>(rh + ro0 + kk);
            const bf16x8 ah1 = *reinterpret_cast<const bf16x8*>(rh + ro0 + 16 * KPAD + kk);
            const bf16x8 ah2 = *reinterpret_cast<const bf16x8*>(rh + ro0 + 32 * KPAD + kk);
            const bf16x8 al0 = *reinterpret_cast<const bf16x8*>(rl + ro0 + kk);
            const bf16x8 al1 = *reinterpret_cast<const bf16x8*>(rl + ro0 + 16 * KPAD + kk);
            const bf16x8 al2 = *reinterpret_cast<const bf16x8*>(rl + ro0 + 32 * KPAD + kk);
            accm[0] = __builtin_amdgcn_mfma_f32_16x16x32_bf16(ah0, wh_f[s], accm[0], 0, 0, 0);
            accm[0] = __builtin_amdgcn_mfma_f32_16x16x32_bf16(ah0, wl_f[s], accm[0], 0, 0, 0);
            accm[0] = __builtin_amdgcn_mfma_f32_16x16x32_bf16(al0, wh_f[s], accm[0], 0, 0, 0);
            accs[0] = __builtin_amdgcn_mfma_f32_16x16x32_bf16(ah0, w2_f[s], accs[0], 0, 0, 0);
            accs[0] = __builtin_amdgcn_mfma_f32_16x16x32_bf16(al0, w2_f[s], accs[0], 0, 0, 0);
            accm[1] = __builtin_amdgcn_mfma_f32_16x16x32_bf16(ah1, wh_f[s], accm[1], 0, 0, 0);
            accm[1] = __builtin_amdgcn_mfma_f32_16x16x32_bf16(ah1, wl_f[s], accm[1], 0, 0, 0);
            accm[1] = __builtin_amdgcn_mfma_f32_16x16x32_bf16(al1, wh_f[s], accm[1], 0, 0, 0);
            accs[1] = __builtin_amdgcn_mfma_f32_16x16x32_bf16(ah1, w2_f[s], accs[1], 0, 0, 0);
            accs[1] = __builtin_amdgcn_mfma_f32_16x16x32_bf16(al1, w2_f[s], accs[1], 0, 0, 0);
            accm[2] = __builtin_amdgcn_mfma_f32_16x16x32_bf16(ah2, wh_f[s], accm[2], 0, 0, 0);
            accm[2] = __builtin_amdgcn_mfma_f32_16x16x32_bf16(ah2, wl_f[s], accm[2], 0, 0, 0);
            accm[2] = __builtin_amdgcn_mfma_f32_16x16x32_bf16(al2, wh_f[s], accm[2], 0, 0, 0);
            accs[2] = __builtin_amdgcn_mfma_f32_16x16x32_bf16(ah2, w2_f[s], accs[2], 0, 0, 0);
            accs[2] = __builtin_amdgcn_mfma_f32_16x16x32_bf16(al2, w2_f[s], accs[2], 0, 0, 0);
        }

        // -------- cross-wave K-reduction --------
        #pragma unroll
        for (int m = 0; m < 3; ++m)
            #pragma unroll
            for (int q = 0; q < 4; ++q){
                red[wv][ln][m * 4 + q]      = accm[m][q];
                red[wv][ln][12 + m * 4 + q] = accs[m][q];
            }
        __syncthreads();

        // -------- epilogue: Phi + update + r split + metric --------
        {
            float ms = 0.0f, ss = 0.0f;
            #pragma unroll
            for (int w = 0; w < 8; ++w){
                ms += red[w][lr0][m0 * 4 + q0];
                ss += red[w][lr0][12 + m0 * 4 + q0];
            }
            const float mu = fmaf(0.01f, ms, im0);
            const float sg = sqrtf(fmaf(0.01f, ss, 25.0f));
            const float rate = phi_rate(mu, sg, isI0 ? 0.001f : 0.005f);
            const float dr = (isI0 ? 0.2f : 0.1f) * (rate - rf0);
            const float rnew = rf0 + dr;
            rf0 = rnew;
            const unsigned short hb = bf16_rne(rnew);
            const float hf = __uint_as_float(((unsigned int)hb) << 16);
            rho[c0 * KPAD + i0n] = hb;
            rlo[c0 * KPAD + i0n] = bf16_rne(rnew - hf);
            vbuf[c_l0][n_l0] = fabsf(dr) / fmaxf(fabsf(rnew), 1.0f);
            if (st == NSTEP - 1) out[i0n * NCOND + c0] = rnew;
        }
        if (has1){
            float ms = 0.0f, ss = 0.0f;
            #pragma unroll
            for (int w = 0; w < 8; ++w){
                ms += red[w][lr1][m1 * 4 + q1];
                ss += red[w][lr1][12 + m1 * 4 + q1];
            }
            const float mu = fmaf(0.01f, ms, im1);
            const float sg = sqrtf(fmaf(0.01f, ss, 25.0f));
            const float rate = phi_rate(mu, sg, isI1 ? 0.001f : 0.005f);
            const float dr = (isI1 ? 0.2f : 0.1f) * (rate - rf1);
            const float rnew = rf1 + dr;
            rf1 = rnew;
            const unsigned short hb = bf16_rne(rnew);
            const float hf = __uint_as_float(((unsigned int)hb) << 16);
            rho[c1 * KPAD + i1n] = hb;
            rlo[c1 * KPAD + i1n] = bf16_rne(rnew - hf);
            vbuf[c_l1][n_l1] = fabsf(dr) / fmaxf(fabsf(rnew), 1.0f);
            if (st == NSTEP - 1) out[i1n * NCOND + c1] = rnew;
        }
        __syncthreads();
        if (t < 48){
            float mx = 0.0f;
            #pragma unroll
            for (int j = 0; j < 16; ++j) mx = fmaxf(mx, vbuf[t][j]);
            atomicMax(mb + st * NCOND + cbase + t, __float_as_uint(mx * 1e5f));
        }

        // -------- grid-wide step boundary: release + sync + acquire --------
        __threadfence();    // write-back dirty L2 (r_out visible device-wide)
        grid.sync();
        __threadfence();    // invalidate caches (see other XCDs' r_out)
    }
}

// ---------------- finalize: avg of last NAVG per-step maxima ----------------
__global__ __launch_bounds__(256) void finalize_kernel(
    const unsigned int* __restrict__ m_buf, float* __restrict__ out)
{
    __shared__ float sbuf[256];
    float s = 0.0f;
    for (int idx = threadIdx.x; idx < (NAVG * NCOND); idx += 256)
        s += __uint_as_float(m_buf[(NSTEP - NAVG) * NCOND + idx]);
    sbuf[threadIdx.x] = s;
    __syncthreads();
    for (int st = 128; st > 0; st >>= 1){
        if (threadIdx.x < st) sbuf[threadIdx.x] += sbuf[threadIdx.x + st];
        __syncthreads();
    }
    if (threadIdx.x == 0) out[N_NEUR * NCOND] = sbuf[0] / (float)(NAVG * NCOND);
}

extern "C" void kernel_launch(void* const* d_in, const int* in_sizes, int n_in,
                              void* d_out, int out_size, void* d_ws, size_t ws_size,
                              hipStream_t stream) {
    const float* jp  = (const float*)d_in[0];
    const float* pp  = (const float*)d_in[1];
    const float* wp  = (const float*)d_in[2];
    const float* rnd = (const float*)d_in[3];
    float* out = (float*)d_out;

    const size_t WELEMS = (size_t)KPAD * KPAD;          // 4,194,304
    const size_t RELEMS = (size_t)NCOND * KPAD;         // 196,608
    unsigned short* Wh  = (unsigned short*)d_ws;
    unsigned short* Wl  = Wh  + WELEMS;
    unsigned short* W2h = Wl  + WELEMS;
    unsigned short* rhA = W2h + WELEMS;
    unsigned short* rlA = rhA + RELEMS;
    unsigned short* rhB = rlA + RELEMS;
    unsigned short* rlB = rhB + RELEMS;
    float* IM = (float*)(rlB + RELEMS);
    unsigned int* mb = (unsigned int*)(IM + RELEMS);    // 60*96

    // zero the 4 r buffers (r0 = 0; pad columns must stay 0) + metric buffer
    hipMemsetAsync(rhA, 0, 4 * RELEMS * sizeof(unsigned short), stream);
    hipMemsetAsync(mb, 0, (size_t)NSTEP * NCOND * sizeof(unsigned int), stream);

    build_w_kernel<<<(int)(WELEMS / 256), 256, 0, stream>>>(jp, pp, wp, rnd, Wh, Wl, W2h);
    build_im_kernel<<<(int)(RELEMS / 256), 256, 0, stream>>>(IM);

    void* args[] = {(void*)&Wh, (void*)&Wl, (void*)&W2h,
                    (void*)&rhA, (void*)&rlA, (void*)&rhB, (void*)&rlB,
                    (void*)&IM, (void*)&out, (void*)&mb};
    hipLaunchCooperativeKernel((const void*)solve_kernel, dim3(250), dim3(512),
                               args, 0, stream);

    finalize_kernel<<<1, 256, 0, stream>>>(mb, out);
}

// Round 6
// 1482.064 us; speedup vs baseline: 4.2784x; 4.2784x over previous
//
#include <hip/hip_runtime.h>
#include <hip/hip_bf16.h>

#define N_NEUR 2000
#define N_E    1600
#define KPAD   2048
#define NCOND  96
#define NSTEP  60
#define NAVG   15
#define NBLK   250
#define RELEMS (NCOND * KPAD)          // 196608 elements per r array

#define DEGF   0.017453292519943295f
#define TWO_DEG 0.03490658503988659f

typedef __attribute__((ext_vector_type(8))) short bf16x8;
typedef __attribute__((ext_vector_type(4))) float f32x4;

// ---------------- Ricciardi transfer function ----------------
__device__ __forceinline__ float f_ricci(float x){
    float t = -x / (1.0f + x);
    float p = 0.14805913578876898f;
    p = fmaf(p, t, 0.64290613877355551f);
    p = fmaf(p, t, 1.0616084849547165f);
    p = fmaf(p, t, 0.93524391761244940f);
    p = fmaf(p, t, 0.62718906618071668f);
    p = fmaf(p, t, 0.32171431660633076f);
    p = fmaf(p, t, 0.32056016125642045f);
    p = fmaf(p, t, 0.77373949685442023f);
    p = fmaf(p, t, 0.22757881388024176f);
    return logf(2.0f * x + 1.0f) + p * t;
}

__device__ __forceinline__ float g_ricci(float x){
    float z = x / (2.0f + x);
    float z2 = z * z, z3 = z2 * z, z4 = z2 * z2, z5 = z4 * z, z6 = z3 * z3, z7 = z6 * z, z8 = z4 * z4;
    float en = 3.5441754117462949f * z - 7.0529131065835378f * z2 - 56.532378057580381f * z3
             + 279.56761105465944f * z4 - 520.37554793489681f * z5
             + 456.58245777026514f * z6 - 155.73340457809226f * z7;
    float de = 1.0f - 4.1357968834226053f * z - 7.2984226138266743f * z2
             + 98.656602235468327f * z3 - 334.20436223415163f * z4
             + 601.08633903294185f * z5 - 599.58577549598340f * z6
             + 277.18420330693891f * z7 - 16.445022798669722f * z8;
    return en / de;
}

__device__ __forceinline__ float phi_rate(float mu, float sigma, float tau_ref){
    const float tau = 0.01f;
    float xp = mu / sigma;
    float xm = (mu - 20.0f) / sigma;
    float r;
    if (xm > 0.0f){
        r = 1.0f / (f_ricci(xp) - f_ricci(xm));
    } else if (xp > 0.0f){
        float nxm = fminf(-xm, 9.0f);
        r = 1.0f / (f_ricci(xp) + expf(nxm * nxm) * g_ricci(nxm));
    } else {
        float nxp = fminf(fmaxf(-xp, 0.0f), 9.0f);
        float nxm = fminf(-xm, 9.0f);
        float arg = g_ricci(nxm) - expf(nxp * nxp - nxm * nxm) * g_ricci(nxp);
        r = expf(-nxm * nxm - logf(fmaxf(arg, 1e-12f)));
    }
    return 1.0f / (tau_ref + tau / fmaxf(r, 1e-12f));
}

__device__ __forceinline__ float pref_of(int n){
    return (n < N_E) ? (float)n * (179.99f / 1599.0f)
                     : (float)(n - N_E) * (179.99f / 399.0f);
}

__device__ __forceinline__ unsigned short bf16_rne(float f){
    unsigned int u = __float_as_uint(f);
    u = (u + 0x7fffu + ((u >> 16) & 1u)) >> 16;
    return (unsigned short)u;
}

// ---------------- weight build: Wh, Wl (split), W2h, padded to 2048x2048 ----------------
__global__ __launch_bounds__(256) void build_w_kernel(
    const float* __restrict__ jp, const float* __restrict__ pp,
    const float* __restrict__ wp, const float* __restrict__ rnd,
    unsigned short* __restrict__ Wh, unsigned short* __restrict__ Wl,
    unsigned short* __restrict__ W2h)
{
    int e = blockIdx.x * 256 + threadIdx.x;     // over 2048*2048
    int i = e >> 11;
    int j = e & (KPAD - 1);
    float w = 0.0f;
    if (i < N_NEUR && j < N_NEUR){
        int isIi = (i >= N_E) ? 1 : 0;
        int isIj = (j >= N_E) ? 1 : 0;
        int conn = 2 * isIj + isIi;
        float J  = expf(jp[conn]);
        float P  = 1.0f / (1.0f + expf(-2.0f * expf(pp[conn])));
        float Wd = expf(wp[conn]);
        float diff = fabsf(pref_of(i) - pref_of(j));
        float dw = DEGF * Wd;
        float z = expf((cosf(TWO_DEG * diff) - 1.0f) / (4.0f * dw * dw));
        float s = 1.0f / (1.0f + expf(-32.0f * (P * z - rnd[i * N_NEUR + j])));
        float sign = isIj ? -1.0f : 1.0f;
        w = sign * J * s;
    }
    unsigned short hb = bf16_rne(w);
    float hf = __uint_as_float(((unsigned int)hb) << 16);
    Wh[e] = hb;
    Wl[e] = bf16_rne(w - hf);
    W2h[e] = bf16_rne(w * w);
}

__global__ __launch_bounds__(256) void build_im_kernel(float* __restrict__ IM)
{
    int e = blockIdx.x * 256 + threadIdx.x;     // over 96*2048
    int c = e >> 11;
    int n = e & (KPAD - 1);
    if (n >= N_NEUR){ IM[e] = 0.0f; return; }
    const float contrasts[8] = {0.0f, 0.0432773f, 0.103411f, 0.186966f,
                                0.303066f, 0.464386f, 0.68854f, 1.0f};
    int ci = c / 12;
    int oi = c - ci * 12;
    float orient = (float)oi * 15.0f;
    const float dw = DEGF * 30.0f;
    float g = expf((cosf(TWO_DEG * (orient - pref_of(n))) - 1.0f) / (4.0f * dw * dw));
    IM[e] = contrasts[ci] * 20.0f * g;
}

// ---------------- device barrier: monotonic counter + spin (no cache fences) ----------
__device__ __forceinline__ void barrier_dev(unsigned int* cnt, unsigned int target, int t)
{
    asm volatile("s_waitcnt vmcnt(0)" ::: "memory");   // all prior VMEM done (per wave)
    __syncthreads();                                   // whole block done
    if (t == 0){
        __hip_atomic_fetch_add(cnt, 1u, __ATOMIC_RELAXED, __HIP_MEMORY_SCOPE_AGENT);
        while (__hip_atomic_load(cnt, __ATOMIC_RELAXED, __HIP_MEMORY_SCOPE_AGENT) < target)
            __builtin_amdgcn_s_sleep(2);
    }
    __syncthreads();
}

// ---------------- persistent solver: all 60 Euler steps, fence-free coherence --------
// grid 250 x 512 (8 waves). Block = (tile = bid>>1 -> 16 neurons, half = bid&1 ->
// 48 conds). W fragments live in VGPRs. Per step:
//   compute from XCD-local scratch (plain cached loads, own-L2 coherent)
//   -> epilogue writes r hi/lo via agent-scope stores (write-through to L3)
//   -> global counter barrier (release = vmcnt only: nothing dirty in L2)
//   -> each physical XCD stages r (hi+lo, 786KB) from L3 into its scratch buffer
//   -> per-XCD counter barrier.
// XCD identity via s_getreg hwreg(20,0,4) = HW_REG_XCC_ID (HW-verified 0..7).
// mu  <- rh*Wh + rh*Wl + rl*Wh ; sg2 <- rh*W2h + rl*W2h   (split-bf16 ~ fp32)
__global__ __launch_bounds__(512, 2) void solve_kernel(
    const unsigned short* __restrict__ Wh, const unsigned short* __restrict__ Wl,
    const unsigned short* __restrict__ W2h,
    unsigned short* __restrict__ rh0, unsigned short* __restrict__ rl0,
    unsigned short* __restrict__ rh1, unsigned short* __restrict__ rl1,
    unsigned short* __restrict__ scrh, unsigned short* __restrict__ scrl,
    const float* __restrict__ IM, float* __restrict__ out,
    unsigned int* __restrict__ mb, unsigned int* __restrict__ cnts)
{
    __shared__ float red[8][64][25];    // padded stride 25: conflict-free
    __shared__ float vbuf[48][16];
    __shared__ int s_g, s_slot, s_M;

    unsigned int* gcnt   = cnts;        // global barrier counter (line 0)
    unsigned int* regcnt = cnts + 32;   // per-XCD registration counters [8]
    unsigned int* xcnt   = cnts + 64;   // per-XCD barrier counters, stride 8 (32B apart)

    const int bid  = blockIdx.x;        // 0..249
    const int tile = bid >> 1;          // 0..124
    const int half = bid & 1;
    const int t  = threadIdx.x;
    const int wv = t >> 6;
    const int ln = t & 63;
    const int nbase = tile * 16;
    const int cbase = half * 48;

    // ---- discover physical XCD, grab a slot within it ----
    if (t == 0){
        unsigned int xcc;
        asm volatile("s_getreg_b32 %0, hwreg(20, 0, 4)" : "=s"(xcc));   // HW_REG_XCC_ID
        int slot = (int)__hip_atomic_fetch_add(&regcnt[xcc & 7], 1u,
                                               __ATOMIC_RELAXED, __HIP_MEMORY_SCOPE_AGENT);
        s_g = (int)(xcc & 7);
        s_slot = slot;
    }
    __syncthreads();
    const int g = s_g;

    const int lrow = ln & 15;           // A-row (cond) / B-col (neuron) in frag
    const int lk8  = (ln >> 4) * 8;     // k sub-offset
    const int kw   = wv * 256 + lk8;    // wave K-slice base + lane sub-k
    const int nrow = nbase + lrow;

    // ---- preload W fragments into registers (constant across steps) ----
    const unsigned short* pwh = &Wh [nrow * KPAD + kw];
    const unsigned short* pwl = &Wl [nrow * KPAD + kw];
    const unsigned short* pw2 = &W2h[nrow * KPAD + kw];
    bf16x8 wh_f[8], wl_f[8], w2_f[8];
    #pragma unroll
    for (int s = 0; s < 8; ++s){
        wh_f[s] = *reinterpret_cast<const bf16x8*>(pwh + s * 32);
        wl_f[s] = *reinterpret_cast<const bf16x8*>(pwl + s * 32);
        w2_f[s] = *reinterpret_cast<const bf16x8*>(pw2 + s * 32);
    }

    // ---- registration barrier; then member count of this XCD group ----
    barrier_dev(gcnt, NBLK, t);
    if (t == 0)
        s_M = (int)__hip_atomic_load(&regcnt[g], __ATOMIC_RELAXED, __HIP_MEMORY_SCOPE_AGENT);
    __syncthreads();
    const int M = s_M;
    const int slot = s_slot;

    // ---- epilogue slot precompute: slot0 = o=t, slot1 = o=t+512 (t<256) ----
    const int o0 = t, o1 = t + 512;
    const bool has1 = (o1 < 768);
    const int c_l0 = o0 >> 4, n_l0 = o0 & 15;
    const int c_l1 = o1 >> 4, n_l1 = o1 & 15;
    const int m0 = c_l0 >> 4, q0 = c_l0 & 3, lr0 = ((c_l0 & 15) >> 2) * 16 + n_l0;
    const int m1 = c_l1 >> 4, q1 = c_l1 & 3, lr1 = ((c_l1 & 15) >> 2) * 16 + n_l1;
    const int c0 = cbase + c_l0, i0n = nbase + n_l0;
    const int c1 = cbase + c_l1, i1n = nbase + n_l1;
    const float im0 = IM[c0 * KPAD + i0n];
    const float im1 = has1 ? IM[c1 * KPAD + i1n] : 0.0f;
    const bool isI0 = (i0n >= N_E), isI1 = (i1n >= N_E);
    float rf0 = 0.0f, rf1 = 0.0f;       // r state in registers

    const int ro0 = (cbase + lrow) * KPAD + kw;   // A-frag base offset
    const int N8 = (RELEMS * 2) / 8;              // 8B words per r array (49152)
    const int chunk = (N8 + M - 1) / M;
    const int stg_lo = slot * chunk;
    const int stg_hi = (stg_lo + chunk < N8) ? (stg_lo + chunk) : N8;

    for (int st = 0; st < NSTEP; ++st){
        const int p_in  = st & 1;
        const int p_out = p_in ^ 1;
        const unsigned short* sh = scrh + ((size_t)g * 2 + p_in) * RELEMS;
        const unsigned short* sl = scrl + ((size_t)g * 2 + p_in) * RELEMS;

        f32x4 accm[3], accs[3];
        #pragma unroll
        for (int m = 0; m < 3; ++m){
            accm[m] = (f32x4){0.0f, 0.0f, 0.0f, 0.0f};
            accs[m] = (f32x4){0.0f, 0.0f, 0.0f, 0.0f};
        }

        #pragma unroll
        for (int s = 0; s < 8; ++s){
            const int kk = s * 32;
            const bf16x8 ah0 = *reinterpret_cast<const bf16x8*>(sh + ro0 + kk);
            const bf16x8 ah1 = *reinterpret_cast<const bf16x8*>(sh + ro0 + 16 * KPAD + kk);
            const bf16x8 ah2 = *reinterpret_cast<const bf16x8*>(sh + ro0 + 32 * KPAD + kk);
            const bf16x8 al0 = *reinterpret_cast<const bf16x8*>(sl + ro0 + kk);
            const bf16x8 al1 = *reinterpret_cast<const bf16x8*>(sl + ro0 + 16 * KPAD + kk);
            const bf16x8 al2 = *reinterpret_cast<const bf16x8*>(sl + ro0 + 32 * KPAD + kk);
            accm[0] = __builtin_amdgcn_mfma_f32_16x16x32_bf16(ah0, wh_f[s], accm[0], 0, 0, 0);
            accm[0] = __builtin_amdgcn_mfma_f32_16x16x32_bf16(ah0, wl_f[s], accm[0], 0, 0, 0);
            accm[0] = __builtin_amdgcn_mfma_f32_16x16x32_bf16(al0, wh_f[s], accm[0], 0, 0, 0);
            accs[0] = __builtin_amdgcn_mfma_f32_16x16x32_bf16(ah0, w2_f[s], accs[0], 0, 0, 0);
            accs[0] = __builtin_amdgcn_mfma_f32_16x16x32_bf16(al0, w2_f[s], accs[0], 0, 0, 0);
            accm[1] = __builtin_amdgcn_mfma_f32_16x16x32_bf16(ah1, wh_f[s], accm[1], 0, 0, 0);
            accm[1] = __builtin_amdgcn_mfma_f32_16x16x32_bf16(ah1, wl_f[s], accm[1], 0, 0, 0);
            accm[1] = __builtin_amdgcn_mfma_f32_16x16x32_bf16(al1, wh_f[s], accm[1], 0, 0, 0);
            accs[1] = __builtin_amdgcn_mfma_f32_16x16x32_bf16(ah1, w2_f[s], accs[1], 0, 0, 0);
            accs[1] = __builtin_amdgcn_mfma_f32_16x16x32_bf16(al1, w2_f[s], accs[1], 0, 0, 0);
            accm[2] = __builtin_amdgcn_mfma_f32_16x16x32_bf16(ah2, wh_f[s], accm[2], 0, 0, 0);
            accm[2] = __builtin_amdgcn_mfma_f32_16x16x32_bf16(ah2, wl_f[s], accm[2], 0, 0, 0);
            accm[2] = __builtin_amdgcn_mfma_f32_16x16x32_bf16(al2, wh_f[s], accm[2], 0, 0, 0);
            accs[2] = __builtin_amdgcn_mfma_f32_16x16x32_bf16(ah2, w2_f[s], accs[2], 0, 0, 0);
            accs[2] = __builtin_amdgcn_mfma_f32_16x16x32_bf16(al2, w2_f[s], accs[2], 0, 0, 0);
        }

        // -------- cross-wave K-reduction --------
        #pragma unroll
        for (int m = 0; m < 3; ++m)
            #pragma unroll
            for (int q = 0; q < 4; ++q){
                red[wv][ln][m * 4 + q]      = accm[m][q];
                red[wv][ln][12 + m * 4 + q] = accs[m][q];
            }
        __syncthreads();

        unsigned short* rho = p_out ? rh1 : rh0;
        unsigned short* rlo = p_out ? rl1 : rl0;

        // -------- epilogue: Phi + update + agent-scope r stores + metric --------
        {
            float ms = 0.0f, ss = 0.0f;
            #pragma unroll
            for (int w = 0; w < 8; ++w){
                ms += red[w][lr0][m0 * 4 + q0];
                ss += red[w][lr0][12 + m0 * 4 + q0];
            }
            const float mu = fmaf(0.01f, ms, im0);
            const float sg = sqrtf(fmaf(0.01f, ss, 25.0f));
            const float rate = phi_rate(mu, sg, isI0 ? 0.001f : 0.005f);
            const float dr = (isI0 ? 0.2f : 0.1f) * (rate - rf0);
            const float rnew = rf0 + dr;
            rf0 = rnew;
            const unsigned short hb = bf16_rne(rnew);
            const float hf = __uint_as_float(((unsigned int)hb) << 16);
            __hip_atomic_store(&rho[c0 * KPAD + i0n], hb,
                               __ATOMIC_RELAXED, __HIP_MEMORY_SCOPE_AGENT);
            __hip_atomic_store(&rlo[c0 * KPAD + i0n], bf16_rne(rnew - hf),
                               __ATOMIC_RELAXED, __HIP_MEMORY_SCOPE_AGENT);
            vbuf[c_l0][n_l0] = fabsf(dr) / fmaxf(fabsf(rnew), 1.0f);
            if (st == NSTEP - 1) out[i0n * NCOND + c0] = rnew;
        }
        if (has1){
            float ms = 0.0f, ss = 0.0f;
            #pragma unroll
            for (int w = 0; w < 8; ++w){
                ms += red[w][lr1][m1 * 4 + q1];
                ss += red[w][lr1][12 + m1 * 4 + q1];
            }
            const float mu = fmaf(0.01f, ms, im1);
            const float sg = sqrtf(fmaf(0.01f, ss, 25.0f));
            const float rate = phi_rate(mu, sg, isI1 ? 0.001f : 0.005f);
            const float dr = (isI1 ? 0.2f : 0.1f) * (rate - rf1);
            const float rnew = rf1 + dr;
            rf1 = rnew;
            const unsigned short hb = bf16_rne(rnew);
            const float hf = __uint_as_float(((unsigned int)hb) << 16);
            __hip_atomic_store(&rho[c1 * KPAD + i1n], hb,
                               __ATOMIC_RELAXED, __HIP_MEMORY_SCOPE_AGENT);
            __hip_atomic_store(&rlo[c1 * KPAD + i1n], bf16_rne(rnew - hf),
                               __ATOMIC_RELAXED, __HIP_MEMORY_SCOPE_AGENT);
            vbuf[c_l1][n_l1] = fabsf(dr) / fmaxf(fabsf(rnew), 1.0f);
            if (st == NSTEP - 1) out[i1n * NCOND + c1] = rnew;
        }
        __syncthreads();
        if (t < 48){
            float mx = 0.0f;
            #pragma unroll
            for (int j = 0; j < 16; ++j) mx = fmaxf(mx, vbuf[t][j]);
            atomicMax(mb + st * NCOND + cbase + t, __float_as_uint(mx * 1e5f));
        }

        if (st == NSTEP - 1) break;     // final r written to out; no more exchange

        // -------- global barrier: all r stores (write-through) are in L3 --------
        barrier_dev(gcnt, (unsigned int)NBLK * (unsigned int)(st + 2), t);

        // -------- stage r (hi+lo) from L3 into this XCD's scratch buffer --------
        {
            const unsigned long long* srcH = (const unsigned long long*)(p_out ? rh1 : rh0);
            const unsigned long long* srcL = (const unsigned long long*)(p_out ? rl1 : rl0);
            unsigned long long* dstH = (unsigned long long*)(scrh + ((size_t)g * 2 + p_out) * RELEMS);
            unsigned long long* dstL = (unsigned long long*)(scrl + ((size_t)g * 2 + p_out) * RELEMS);
            for (int idx = stg_lo + t; idx < stg_hi; idx += 512){
                dstH[idx] = __hip_atomic_load(&srcH[idx], __ATOMIC_RELAXED, __HIP_MEMORY_SCOPE_AGENT);
                dstL[idx] = __hip_atomic_load(&srcL[idx], __ATOMIC_RELAXED, __HIP_MEMORY_SCOPE_AGENT);
            }
        }

        // -------- per-XCD barrier: scratch[p_out] complete in this XCD's L2 --------
        barrier_dev(&xcnt[g * 8], (unsigned int)M * (unsigned int)(st + 1), t);
    }
}

// ---------------- finalize: avg of last NAVG per-step maxima ----------------
__global__ __launch_bounds__(256) void finalize_kernel(
    const unsigned int* __restrict__ m_buf, float* __restrict__ out)
{
    __shared__ float sbuf[256];
    float s = 0.0f;
    for (int idx = threadIdx.x; idx < (NAVG * NCOND); idx += 256)
        s += __uint_as_float(m_buf[(NSTEP - NAVG) * NCOND + idx]);
    sbuf[threadIdx.x] = s;
    __syncthreads();
    for (int st = 128; st > 0; st >>= 1){
        if (threadIdx.x < st) sbuf[threadIdx.x] += sbuf[threadIdx.x + st];
        __syncthreads();
    }
    if (threadIdx.x == 0) out[N_NEUR * NCOND] = sbuf[0] / (float)(NAVG * NCOND);
}

extern "C" void kernel_launch(void* const* d_in, const int* in_sizes, int n_in,
                              void* d_out, int out_size, void* d_ws, size_t ws_size,
                              hipStream_t stream) {
    const float* jp  = (const float*)d_in[0];
    const float* pp  = (const float*)d_in[1];
    const float* wp  = (const float*)d_in[2];
    const float* rnd = (const float*)d_in[3];
    float* out = (float*)d_out;

    const size_t WELEMS = (size_t)KPAD * KPAD;          // 4,194,304
    unsigned short* Wh  = (unsigned short*)d_ws;
    unsigned short* Wl  = Wh  + WELEMS;
    unsigned short* W2h = Wl  + WELEMS;
    float* IM = (float*)(W2h + WELEMS);
    // ---- zeroed region starts here ----
    unsigned short* rh0 = (unsigned short*)(IM + RELEMS);
    unsigned short* rl0 = rh0 + RELEMS;
    unsigned short* rh1 = rl0 + RELEMS;
    unsigned short* rl1 = rh1 + RELEMS;
    unsigned short* scrh = rl1 + RELEMS;                // 8 groups x 2 bufs x RELEMS
    unsigned short* scrl = scrh + (size_t)16 * RELEMS;
    unsigned int* mb   = (unsigned int*)(scrl + (size_t)16 * RELEMS);   // 60*96
    unsigned int* cnts = mb + (size_t)NSTEP * NCOND;                    // 128 uints
    const size_t zero_bytes = (size_t)((char*)(cnts + 128) - (char*)rh0);

    hipMemsetAsync(rh0, 0, zero_bytes, stream);

    build_w_kernel<<<(int)(WELEMS / 256), 256, 0, stream>>>(jp, pp, wp, rnd, Wh, Wl, W2h);
    build_im_kernel<<<(int)(RELEMS / 256), 256, 0, stream>>>(IM);

    void* args[] = {(void*)&Wh, (void*)&Wl, (void*)&W2h,
                    (void*)&rh0, (void*)&rl0, (void*)&rh1, (void*)&rl1,
                    (void*)&scrh, (void*)&scrl,
                    (void*)&IM, (void*)&out, (void*)&mb, (void*)&cnts};
    hipLaunchCooperativeKernel((const void*)solve_kernel, dim3(NBLK), dim3(512),
                               args, 0, stream);

    finalize_kernel<<<1, 256, 0, stream>>>(mb, out);
}

// Round 8
// 1321.927 us; speedup vs baseline: 4.7967x; 1.1211x over previous
//
#include <hip/hip_runtime.h>
#include <hip/hip_bf16.h>

#define N_NEUR 2000
#define N_E    1600
#define KPAD   2048
#define NCOND  96
#define NSTEP  60
#define NAVG   15
#define NBLK   250
#define RELEMS (NCOND * KPAD)          // 196608 elements per r array
#define N8     49152                   // 8B words per r array (RELEMS*2B/8)

// counter slots (uint indices into cnts[]; 128B line separation for hot words)
#define RCNT   0        // registration counter
#define REL    32       // barrier release word
#define REGC   64       // [8] per-XCD registration counters
#define FLAGS  256      // + bid*16 : per-block barrier flag (64B stride)

#define DEGF   0.017453292519943295f
#define TWO_DEG 0.03490658503988659f

typedef __attribute__((ext_vector_type(8))) short bf16x8;
typedef __attribute__((ext_vector_type(4))) float f32x4;

// ---------------- Ricciardi transfer function ----------------
__device__ __forceinline__ float f_ricci(float x){
    float t = -x / (1.0f + x);
    float p = 0.14805913578876898f;
    p = fmaf(p, t, 0.64290613877355551f);
    p = fmaf(p, t, 1.0616084849547165f);
    p = fmaf(p, t, 0.93524391761244940f);
    p = fmaf(p, t, 0.62718906618071668f);
    p = fmaf(p, t, 0.32171431660633076f);
    p = fmaf(p, t, 0.32056016125642045f);
    p = fmaf(p, t, 0.77373949685442023f);
    p = fmaf(p, t, 0.22757881388024176f);
    return logf(2.0f * x + 1.0f) + p * t;
}

__device__ __forceinline__ float g_ricci(float x){
    float z = x / (2.0f + x);
    float z2 = z * z, z3 = z2 * z, z4 = z2 * z2, z5 = z4 * z, z6 = z3 * z3, z7 = z6 * z, z8 = z4 * z4;
    float en = 3.5441754117462949f * z - 7.0529131065835378f * z2 - 56.532378057580381f * z3
             + 279.56761105465944f * z4 - 520.37554793489681f * z5
             + 456.58245777026514f * z6 - 155.73340457809226f * z7;
    float de = 1.0f - 4.1357968834226053f * z - 7.2984226138266743f * z2
             + 98.656602235468327f * z3 - 334.20436223415163f * z4
             + 601.08633903294185f * z5 - 599.58577549598340f * z6
             + 277.18420330693891f * z7 - 16.445022798669722f * z8;
    return en / de;
}

__device__ __forceinline__ float phi_rate(float mu, float sigma, float tau_ref){
    const float tau = 0.01f;
    float xp = mu / sigma;
    float xm = (mu - 20.0f) / sigma;
    float r;
    if (xm > 0.0f){
        r = 1.0f / (f_ricci(xp) - f_ricci(xm));
    } else if (xp > 0.0f){
        float nxm = fminf(-xm, 9.0f);
        r = 1.0f / (f_ricci(xp) + expf(nxm * nxm) * g_ricci(nxm));
    } else {
        float nxp = fminf(fmaxf(-xp, 0.0f), 9.0f);
        float nxm = fminf(-xm, 9.0f);
        float arg = g_ricci(nxm) - expf(nxp * nxp - nxm * nxm) * g_ricci(nxp);
        r = expf(-nxm * nxm - logf(fmaxf(arg, 1e-12f)));
    }
    return 1.0f / (tau_ref + tau / fmaxf(r, 1e-12f));
}

__device__ __forceinline__ float pref_of(int n){
    return (n < N_E) ? (float)n * (179.99f / 1599.0f)
                     : (float)(n - N_E) * (179.99f / 399.0f);
}

__device__ __forceinline__ unsigned short bf16_rne(float f){
    unsigned int u = __float_as_uint(f);
    u = (u + 0x7fffu + ((u >> 16) & 1u)) >> 16;
    return (unsigned short)u;
}

__device__ __forceinline__ void vmdrain(){
    asm volatile("s_waitcnt vmcnt(0)" ::: "memory");
}

// ---------------- weight build: Wh, Wl (split), W2h, padded to 2048x2048 ----------------
__global__ __launch_bounds__(256) void build_w_kernel(
    const float* __restrict__ jp, const float* __restrict__ pp,
    const float* __restrict__ wp, const float* __restrict__ rnd,
    unsigned short* __restrict__ Wh, unsigned short* __restrict__ Wl,
    unsigned short* __restrict__ W2h)
{
    int e = blockIdx.x * 256 + threadIdx.x;     // over 2048*2048
    int i = e >> 11;
    int j = e & (KPAD - 1);
    float w = 0.0f;
    if (i < N_NEUR && j < N_NEUR){
        int isIi = (i >= N_E) ? 1 : 0;
        int isIj = (j >= N_E) ? 1 : 0;
        int conn = 2 * isIj + isIi;
        float J  = expf(jp[conn]);
        float P  = 1.0f / (1.0f + expf(-2.0f * expf(pp[conn])));
        float Wd = expf(wp[conn]);
        float diff = fabsf(pref_of(i) - pref_of(j));
        float dw = DEGF * Wd;
        float z = expf((cosf(TWO_DEG * diff) - 1.0f) / (4.0f * dw * dw));
        float s = 1.0f / (1.0f + expf(-32.0f * (P * z - rnd[i * N_NEUR + j])));
        float sign = isIj ? -1.0f : 1.0f;
        w = sign * J * s;
    }
    unsigned short hb = bf16_rne(w);
    float hf = __uint_as_float(((unsigned int)hb) << 16);
    Wh[e] = hb;
    Wl[e] = bf16_rne(w - hf);
    W2h[e] = bf16_rne(w * w);
}

__global__ __launch_bounds__(256) void build_im_kernel(float* __restrict__ IM)
{
    int e = blockIdx.x * 256 + threadIdx.x;     // over 96*2048
    int c = e >> 11;
    int n = e & (KPAD - 1);
    if (n >= N_NEUR){ IM[e] = 0.0f; return; }
    const float contrasts[8] = {0.0f, 0.0432773f, 0.103411f, 0.186966f,
                                0.303066f, 0.464386f, 0.68854f, 1.0f};
    int ci = c / 12;
    int oi = c - ci * 12;
    float orient = (float)oi * 15.0f;
    const float dw = DEGF * 30.0f;
    float g = expf((cosf(TWO_DEG * (orient - pref_of(n))) - 1.0f) / (4.0f * dw * dw));
    IM[e] = contrasts[ci] * 20.0f * g;
}

// ---------------- flag/scan global barrier (agent-scope ops only) ----------------
// Every block: store own flag = V. Block 0's wave 0 sweeps all flags (64 lanes x 4,
// all loads in flight), then lane 0 stores release = V. Others poll release.
__device__ __forceinline__ void flag_barrier(unsigned int* cnts, int bid, int t,
                                             unsigned int V)
{
    vmdrain();          // every wave: prior vmem (incl. agent stores) complete
    __syncthreads();
    if (t == 0)
        __hip_atomic_store(&cnts[FLAGS + bid * 16], V,
                           __ATOMIC_RELAXED, __HIP_MEMORY_SCOPE_AGENT);
    if (bid == 0){
        if (t < 64){
            for (;;){
                bool ok = true;
                #pragma unroll
                for (int u = 0; u < 4; ++u){
                    int idx = t + u * 64;
                    if (idx < NBLK)
                        ok = ok && (__hip_atomic_load(&cnts[FLAGS + idx * 16],
                                     __ATOMIC_RELAXED, __HIP_MEMORY_SCOPE_AGENT) >= V);
                }
                if (__all(ok)) break;
                __builtin_amdgcn_s_sleep(1);
            }
            if (t == 0)
                __hip_atomic_store(&cnts[REL], V,
                                   __ATOMIC_RELAXED, __HIP_MEMORY_SCOPE_AGENT);
        }
    } else if (t == 0){
        while (__hip_atomic_load(&cnts[REL], __ATOMIC_RELAXED,
                                 __HIP_MEMORY_SCOPE_AGENT) < V)
            __builtin_amdgcn_s_sleep(1);
    }
    __syncthreads();
}

// ---------------- persistent solver: all 60 Euler steps ----------------
// grid 250 x 512 (8 waves), 1 block/CU. Block = (tile = bid>>1 -> 16 neurons,
// half = bid&1 -> 48 conds). W frags in VGPRs across steps. Per step:
//   compute from XCD-local scratch (plain cached loads, own-L2 coherent)
//   -> epilogue: Phi + agent-scope (L3 write-through) r stores
//   -> flag/scan global barrier (phase A)
//   -> per-XCD staging: 8B agent loads from L3 -> plain stores to XCD scratch
//   -> flag/scan global barrier (phase B).
__global__ __launch_bounds__(512, 2) void solve_kernel(
    const unsigned short* __restrict__ Wh, const unsigned short* __restrict__ Wl,
    const unsigned short* __restrict__ W2h,
    unsigned short* __restrict__ rh0, unsigned short* __restrict__ rl0,
    unsigned short* __restrict__ rh1, unsigned short* __restrict__ rl1,
    unsigned short* __restrict__ scrh, unsigned short* __restrict__ scrl,
    const float* __restrict__ IM, float* __restrict__ out,
    float* __restrict__ mloc, unsigned int* __restrict__ cnts)
{
    __shared__ float red[8][64][25];
    __shared__ float vbuf[48][16];
    __shared__ int s_g, s_slot, s_M;

    const int bid  = blockIdx.x;        // 0..249
    const int tile = bid >> 1;          // 0..124
    const int half = bid & 1;
    const int t  = threadIdx.x;
    const int wv = t >> 6;
    const int ln = t & 63;
    const int nbase = tile * 16;
    const int cbase = half * 48;

    // ---- discover physical XCD, register (proven round-6 path) ----
    if (t == 0){
        unsigned int xcc;
        asm volatile("s_getreg_b32 %0, hwreg(20, 0, 4)" : "=s"(xcc));   // HW_REG_XCC_ID
        int g = (int)(xcc & 7);
        int slot = (int)__hip_atomic_fetch_add(&cnts[REGC + g], 1u,
                                               __ATOMIC_RELAXED, __HIP_MEMORY_SCOPE_AGENT);
        vmdrain();   // regcnt add complete before rcnt arrival
        __hip_atomic_fetch_add(&cnts[RCNT], 1u, __ATOMIC_RELAXED, __HIP_MEMORY_SCOPE_AGENT);
        s_g = g; s_slot = slot;
    }
    __syncthreads();
    const int g = s_g;

    const int lrow = ln & 15;
    const int lk8  = (ln >> 4) * 8;
    const int kw   = wv * 256 + lk8;
    const int nrow = nbase + lrow;

    // ---- preload W fragments (constant across steps) ----
    const unsigned short* pwh = &Wh [nrow * KPAD + kw];
    const unsigned short* pwl = &Wl [nrow * KPAD + kw];
    const unsigned short* pw2 = &W2h[nrow * KPAD + kw];
    bf16x8 wh_f[8], wl_f[8], w2_f[8];
    #pragma unroll
    for (int s = 0; s < 8; ++s){
        wh_f[s] = *reinterpret_cast<const bf16x8*>(pwh + s * 32);
        wl_f[s] = *reinterpret_cast<const bf16x8*>(pwl + s * 32);
        w2_f[s] = *reinterpret_cast<const bf16x8*>(pw2 + s * 32);
    }

    // ---- wait for all registrations; M = members of this XCD group ----
    if (t == 0){
        while (__hip_atomic_load(&cnts[RCNT], __ATOMIC_RELAXED, __HIP_MEMORY_SCOPE_AGENT) < NBLK)
            __builtin_amdgcn_s_sleep(4);
        s_M = (int)__hip_atomic_load(&cnts[REGC + g], __ATOMIC_RELAXED, __HIP_MEMORY_SCOPE_AGENT);
    }
    __syncthreads();
    const int M = s_M, slot = s_slot;

    // staging range over N8 8B-words (each idx copies hi AND lo)
    const int chunk = (N8 + M - 1) / M;
    const int stg_lo = slot * chunk;
    const int stg_hi = (stg_lo + chunk < N8) ? (stg_lo + chunk) : N8;

    // ---- epilogue slot precompute ----
    const int o0 = t, o1 = t + 512;
    const bool has1 = (o1 < 768);
    const int c_l0 = o0 >> 4, n_l0 = o0 & 15;
    const int c_l1 = o1 >> 4, n_l1 = o1 & 15;
    const int m0 = c_l0 >> 4, q0 = c_l0 & 3, lr0 = ((c_l0 & 15) >> 2) * 16 + n_l0;
    const int m1 = c_l1 >> 4, q1 = c_l1 & 3, lr1 = ((c_l1 & 15) >> 2) * 16 + n_l1;
    const int c0 = cbase + c_l0, i0n = nbase + n_l0;
    const int c1 = cbase + c_l1, i1n = nbase + n_l1;
    const float im0 = IM[c0 * KPAD + i0n];
    const float im1 = has1 ? IM[c1 * KPAD + i1n] : 0.0f;
    const bool isI0 = (i0n >= N_E), isI1 = (i1n >= N_E);
    float rf0 = 0.0f, rf1 = 0.0f;

    const int ro0 = (cbase + lrow) * KPAD + kw;

    for (int st = 0; st < NSTEP; ++st){
        const int p_in  = st & 1;
        const int p_out = p_in ^ 1;
        const unsigned short* sh = scrh + ((size_t)g * 2 + p_in) * RELEMS;
        const unsigned short* sl = scrl + ((size_t)g * 2 + p_in) * RELEMS;

        f32x4 accm[3], accs[3];
        #pragma unroll
        for (int m = 0; m < 3; ++m){
            accm[m] = (f32x4){0.0f, 0.0f, 0.0f, 0.0f};
            accs[m] = (f32x4){0.0f, 0.0f, 0.0f, 0.0f};
        }

        #pragma unroll
        for (int s = 0; s < 8; ++s){
            const int kk = s * 32;
            const bf16x8 ah0 = *reinterpret_cast<const bf16x8*>(sh + ro0 + kk);
            const bf16x8 ah1 = *reinterpret_cast<const bf16x8*>(sh + ro0 + 16 * KPAD + kk);
            const bf16x8 ah2 = *reinterpret_cast<const bf16x8*>(sh + ro0 + 32 * KPAD + kk);
            const bf16x8 al0 = *reinterpret_cast<const bf16x8*>(sl + ro0 + kk);
            const bf16x8 al1 = *reinterpret_cast<const bf16x8*>(sl + ro0 + 16 * KPAD + kk);
            const bf16x8 al2 = *reinterpret_cast<const bf16x8*>(sl + ro0 + 32 * KPAD + kk);
            accm[0] = __builtin_amdgcn_mfma_f32_16x16x32_bf16(ah0, wh_f[s], accm[0], 0, 0, 0);
            accm[0] = __builtin_amdgcn_mfma_f32_16x16x32_bf16(ah0, wl_f[s], accm[0], 0, 0, 0);
            accm[0] = __builtin_amdgcn_mfma_f32_16x16x32_bf16(al0, wh_f[s], accm[0], 0, 0, 0);
            accs[0] = __builtin_amdgcn_mfma_f32_16x16x32_bf16(ah0, w2_f[s], accs[0], 0, 0, 0);
            accs[0] = __builtin_amdgcn_mfma_f32_16x16x32_bf16(al0, w2_f[s], accs[0], 0, 0, 0);
            accm[1] = __builtin_amdgcn_mfma_f32_16x16x32_bf16(ah1, wh_f[s], accm[1], 0, 0, 0);
            accm[1] = __builtin_amdgcn_mfma_f32_16x16x32_bf16(ah1, wl_f[s], accm[1], 0, 0, 0);
            accm[1] = __builtin_amdgcn_mfma_f32_16x16x32_bf16(al1, wh_f[s], accm[1], 0, 0, 0);
            accs[1] = __builtin_amdgcn_mfma_f32_16x16x32_bf16(ah1, w2_f[s], accs[1], 0, 0, 0);
            accs[1] = __builtin_amdgcn_mfma_f32_16x16x32_bf16(al1, w2_f[s], accs[1], 0, 0, 0);
            accm[2] = __builtin_amdgcn_mfma_f32_16x16x32_bf16(ah2, wh_f[s], accm[2], 0, 0, 0);
            accm[2] = __builtin_amdgcn_mfma_f32_16x16x32_bf16(ah2, wl_f[s], accm[2], 0, 0, 0);
            accm[2] = __builtin_amdgcn_mfma_f32_16x16x32_bf16(al2, wh_f[s], accm[2], 0, 0, 0);
            accs[2] = __builtin_amdgcn_mfma_f32_16x16x32_bf16(ah2, w2_f[s], accs[2], 0, 0, 0);
            accs[2] = __builtin_amdgcn_mfma_f32_16x16x32_bf16(al2, w2_f[s], accs[2], 0, 0, 0);
        }

        // -------- cross-wave K-reduction --------
        #pragma unroll
        for (int m = 0; m < 3; ++m)
            #pragma unroll
            for (int q = 0; q < 4; ++q){
                red[wv][ln][m * 4 + q]      = accm[m][q];
                red[wv][ln][12 + m * 4 + q] = accs[m][q];
            }
        __syncthreads();

        unsigned short* rho = p_out ? rh1 : rh0;
        unsigned short* rlo = p_out ? rl1 : rl0;
        const bool track = (st >= NSTEP - NAVG);

        // -------- epilogue --------
        {
            float ms = 0.0f, ss = 0.0f;
            #pragma unroll
            for (int w = 0; w < 8; ++w){
                ms += red[w][lr0][m0 * 4 + q0];
                ss += red[w][lr0][12 + m0 * 4 + q0];
            }
            const float mu = fmaf(0.01f, ms, im0);
            const float sg = sqrtf(fmaf(0.01f, ss, 25.0f));
            const float rate = phi_rate(mu, sg, isI0 ? 0.001f : 0.005f);
            const float dr = (isI0 ? 0.2f : 0.1f) * (rate - rf0);
            const float rnew = rf0 + dr;
            rf0 = rnew;
            const unsigned short hb = bf16_rne(rnew);
            const float hf = __uint_as_float(((unsigned int)hb) << 16);
            __hip_atomic_store(&rho[c0 * KPAD + i0n], hb,
                               __ATOMIC_RELAXED, __HIP_MEMORY_SCOPE_AGENT);
            __hip_atomic_store(&rlo[c0 * KPAD + i0n], bf16_rne(rnew - hf),
                               __ATOMIC_RELAXED, __HIP_MEMORY_SCOPE_AGENT);
            if (track) vbuf[c_l0][n_l0] = fabsf(dr) / fmaxf(fabsf(rnew), 1.0f);
            if (st == NSTEP - 1) out[i0n * NCOND + c0] = rnew;
        }
        if (has1){
            float ms = 0.0f, ss = 0.0f;
            #pragma unroll
            for (int w = 0; w < 8; ++w){
                ms += red[w][lr1][m1 * 4 + q1];
                ss += red[w][lr1][12 + m1 * 4 + q1];
            }
            const float mu = fmaf(0.01f, ms, im1);
            const float sg = sqrtf(fmaf(0.01f, ss, 25.0f));
            const float rate = phi_rate(mu, sg, isI1 ? 0.001f : 0.005f);
            const float dr = (isI1 ? 0.2f : 0.1f) * (rate - rf1);
            const float rnew = rf1 + dr;
            rf1 = rnew;
            const unsigned short hb = bf16_rne(rnew);
            const float hf = __uint_as_float(((unsigned int)hb) << 16);
            __hip_atomic_store(&rho[c1 * KPAD + i1n], hb,
                               __ATOMIC_RELAXED, __HIP_MEMORY_SCOPE_AGENT);
            __hip_atomic_store(&rlo[c1 * KPAD + i1n], bf16_rne(rnew - hf),
                               __ATOMIC_RELAXED, __HIP_MEMORY_SCOPE_AGENT);
            if (track) vbuf[c_l1][n_l1] = fabsf(dr) / fmaxf(fabsf(rnew), 1.0f);
            if (st == NSTEP - 1) out[i1n * NCOND + c1] = rnew;
        }
        if (track){
            __syncthreads();
            if (t < 48){
                float mx = 0.0f;
                #pragma unroll
                for (int j = 0; j < 16; ++j) mx = fmaxf(mx, vbuf[t][j]);
                mloc[((size_t)(st - (NSTEP - NAVG)) * NBLK + bid) * 48 + t] = mx;
            }
        }
        if (st == NSTEP - 1) break;

        // -------- phase A: global barrier (r stores visible in L3) --------
        flag_barrier(cnts, bid, t, 2u * (unsigned int)st + 1u);

        // -------- staging: L3 -> XCD scratch (8B agent loads, plain stores) ----
        {
            const unsigned long long* srcH = (const unsigned long long*)rho;
            const unsigned long long* srcL = (const unsigned long long*)rlo;
            unsigned long long* dstH = (unsigned long long*)(scrh + ((size_t)g * 2 + p_out) * RELEMS);
            unsigned long long* dstL = (unsigned long long*)(scrl + ((size_t)g * 2 + p_out) * RELEMS);
            for (int idx = stg_lo + t; idx < stg_hi; idx += 512){
                dstH[idx] = __hip_atomic_load(&srcH[idx], __ATOMIC_RELAXED, __HIP_MEMORY_SCOPE_AGENT);
                dstL[idx] = __hip_atomic_load(&srcL[idx], __ATOMIC_RELAXED, __HIP_MEMORY_SCOPE_AGENT);
            }
        }

        // -------- phase B: global barrier (scratch staged everywhere) --------
        flag_barrier(cnts, bid, t, 2u * (unsigned int)st + 2u);
    }
}

// ---------------- finalize A: cross-block max per (step, cond) ----------------
__global__ __launch_bounds__(128) void finalize_max_kernel(
    const float* __restrict__ mloc, float* __restrict__ m2)
{
    int idx = blockIdx.x * 128 + threadIdx.x;   // over 15*96 = 1440
    if (idx >= NAVG * NCOND) return;
    int st = idx / NCOND, c = idx - st * NCOND;
    int half = c / 48, cl = c - half * 48;
    float mx = 0.0f;
    for (int tile = 0; tile < 125; ++tile)
        mx = fmaxf(mx, mloc[((size_t)st * NBLK + tile * 2 + half) * 48 + cl]);
    m2[idx] = mx;
}

// ---------------- finalize B: mean over 15x96, scale by 1/XTOL ----------------
__global__ __launch_bounds__(256) void finalize_sum_kernel(
    const float* __restrict__ m2, float* __restrict__ out)
{
    __shared__ float sbuf[256];
    float s = 0.0f;
    for (int i = threadIdx.x; i < NAVG * NCOND; i += 256) s += m2[i];
    sbuf[threadIdx.x] = s;
    __syncthreads();
    for (int st = 128; st > 0; st >>= 1){
        if (threadIdx.x < st) sbuf[threadIdx.x] += sbuf[threadIdx.x + st];
        __syncthreads();
    }
    if (threadIdx.x == 0)
        out[N_NEUR * NCOND] = sbuf[0] / (float)(NAVG * NCOND) * 1e5f;
}

extern "C" void kernel_launch(void* const* d_in, const int* in_sizes, int n_in,
                              void* d_out, int out_size, void* d_ws, size_t ws_size,
                              hipStream_t stream) {
    const float* jp  = (const float*)d_in[0];
    const float* pp  = (const float*)d_in[1];
    const float* wp  = (const float*)d_in[2];
    const float* rnd = (const float*)d_in[3];
    float* out = (float*)d_out;

    const size_t WELEMS = (size_t)KPAD * KPAD;
    unsigned short* Wh  = (unsigned short*)d_ws;
    unsigned short* Wl  = Wh  + WELEMS;
    unsigned short* W2h = Wl  + WELEMS;
    float* IM   = (float*)(W2h + WELEMS);
    float* mloc = IM + RELEMS;                          // 15*250*48 (fully rewritten)
    float* m2   = mloc + (size_t)NAVG * NBLK * 48;      // 1440 (fully rewritten)
    // ---- zeroed region ----
    unsigned short* rh0 = (unsigned short*)(m2 + NAVG * NCOND);
    unsigned short* rl0 = rh0 + RELEMS;
    unsigned short* rh1 = rl0 + RELEMS;
    unsigned short* rl1 = rh1 + RELEMS;
    unsigned short* scrh = rl1 + RELEMS;                // 8 XCDs x 2 bufs
    unsigned short* scrl = scrh + (size_t)16 * RELEMS;
    unsigned int* cnts = (unsigned int*)(scrl + (size_t)16 * RELEMS);   // 8192 uints
    const size_t zero_bytes = (size_t)((char*)(cnts + 8192) - (char*)rh0);

    hipMemsetAsync(rh0, 0, zero_bytes, stream);

    build_w_kernel<<<(int)(WELEMS / 256), 256, 0, stream>>>(jp, pp, wp, rnd, Wh, Wl, W2h);
    build_im_kernel<<<(int)(RELEMS / 256), 256, 0, stream>>>(IM);

    void* args[] = {(void*)&Wh, (void*)&Wl, (void*)&W2h,
                    (void*)&rh0, (void*)&rl0, (void*)&rh1, (void*)&rl1,
                    (void*)&scrh, (void*)&scrl,
                    (void*)&IM, (void*)&out, (void*)&mloc, (void*)&cnts};
    hipLaunchCooperativeKernel((const void*)solve_kernel, dim3(NBLK), dim3(512),
                               args, 0, stream);

    finalize_max_kernel<<<(NAVG * NCOND + 127) / 128, 128, 0, stream>>>(mloc, m2);
    finalize_sum_kernel<<<1, 256, 0, stream>>>(m2, out);
}